// Round 20
// baseline (122.960 us; speedup 1.0000x reference)
//
#include <hip/hip_runtime.h>
#include <hip/hip_bf16.h>
#include <stdint.h>

#define NN 2048
#define DD 1024
#define HH 16
#define HDD 64
#define QBLK 64
#define KVBLK 128

typedef unsigned short u16;
typedef __attribute__((ext_vector_type(8))) __bf16 bf16x8_t;
typedef __attribute__((ext_vector_type(4))) float f32x4_t;

#define LOG2E 1.44269504f

static __device__ __forceinline__ u16 f2bf(float f) {
  union { float f; uint32_t u; } v; v.f = f;
  uint32_t r = v.u + 0x7FFFu + ((v.u >> 16) & 1u);
  return (u16)(r >> 16);
}

static __device__ __forceinline__ uint32_t packbf2(float a, float b) {
  __hip_bfloat162 h2 = __float22bfloat162_rn(make_float2(a, b));
  union { __hip_bfloat162 hh; uint32_t u; } cvt; cvt.hh = h2;
  return cvt.u;
}

// raw v_exp_f32: computes 2^x in ONE instruction (no libm slow path)
static __device__ __forceinline__ float exp2_raw(float x) {
  float r;
  asm("v_exp_f32 %0, %1" : "=v"(r) : "v"(x));
  return r;
}

// async global->LDS, 16B per lane. LDS dest must be wave-uniform base + lane*16.
static __device__ __forceinline__ void async_copy16(const void* g, void* l) {
  __builtin_amdgcn_global_load_lds((const __attribute__((address_space(1))) void*)g,
                                   (__attribute__((address_space(3))) void*)l, 16, 0, 0);
}

// ---------------- fused prep: logf (blocks 0..4095) + weight transpose (blocks 4096..5119) ----------------
__global__ void prep_kernel(const float* __restrict__ x, const float* __restrict__ Wf,
                            float* __restrict__ lf, u16* __restrict__ xb,
                            const float* __restrict__ W0, const float* __restrict__ W1,
                            const float* __restrict__ W2, const float* __restrict__ W3,
                            u16* __restrict__ Wt) {
  __shared__ float xs[DD];
  __shared__ float part[16][17];
  __shared__ float tile[64][65];
  int t = threadIdx.x;  // 256
  if (blockIdx.x < 4096) {
    int row = blockIdx.x;   // b*N + n
    float4 v = *(const float4*)&x[(size_t)row * DD + t * 4];
    *(float4*)&xs[t * 4] = v;
    ushort4 o;
    o.x = f2bf(v.x); o.y = f2bf(v.y); o.z = f2bf(v.z); o.w = f2bf(v.w);
    *(ushort4*)&xb[(size_t)row * DD + t * 4] = o;
    __syncthreads();
    int h = t & 15, chunk = t >> 4;
    float s = 0.f;
#pragma unroll 8
    for (int e = 0; e < 64; e++)
      s += xs[chunk * 64 + e] * Wf[(chunk * 64 + e) * HH + h];
    part[chunk][h] = s;
    __syncthreads();
    if (t < 16) {
      float z = 0.f;
#pragma unroll
      for (int i = 0; i < 16; i++) z += part[i][t];
      float ls = fminf(z, 0.f) - log1pf(__expf(-fabsf(z)));
      int b = row >> 11, n = row & (NN - 1);
      lf[(b * HH + t) * NN + n] = ls;
    }
  } else {
    int bid = blockIdx.x - 4096;
    int wq = bid >> 8;  // which weight
    const float* W = wq == 0 ? W0 : wq == 1 ? W1 : wq == 2 ? W2 : W3;
    u16* out = Wt + (size_t)wq * DD * DD;
    int bx = bid & 15;          // n tile
    int by = (bid >> 4) & 15;   // k tile
    int c = t & 63, r4 = t >> 6;
#pragma unroll
    for (int i = 0; i < 16; i++) {
      int row = i * 4 + r4;
      tile[row][c] = W[(by * 64 + row) * DD + bx * 64 + c];
    }
    __syncthreads();
#pragma unroll
    for (int i = 0; i < 16; i++) {
      int row = i * 4 + r4;
      out[(bx * 64 + row) * DD + by * 64 + c] = f2bf(tile[c][row]);
    }
  }
}

// ---------------- cumsum over n per (b,h): float4/lane; OUTPUT PRE-SCALED by log2(e) ----------------
__global__ void cumsum_kernel(const float* __restrict__ lf, float* __restrict__ c) {
  int bh = blockIdx.x;
  int lane = threadIdx.x;  // 64
  const float* in = lf + bh * NN;
  float* out = c + bh * NN;
  float carry = 0.f;
  for (int t0 = 0; t0 < NN; t0 += 256) {
    float4 v = *(const float4*)&in[t0 + lane * 4];
    float s1 = v.x + v.y, s2 = s1 + v.z, s3 = s2 + v.w;
    float incl = s3;
#pragma unroll
    for (int off = 1; off < 64; off <<= 1) {
      float u = __shfl_up(incl, off, 64);
      if (lane >= off) incl += u;
    }
    float excl = incl - s3 + carry;
    float4 o;
    o.x = (excl + v.x) * LOG2E; o.y = (excl + s1) * LOG2E;
    o.z = (excl + s2) * LOG2E; o.w = (excl + s3) * LOG2E;
    *(float4*)&out[t0 + lane * 4] = o;
    carry = __shfl(incl, 63, 64) + carry;
  }
}

// ---------------- QKV GEMM: m97-proven shape -- 256 threads, 2x2 waves, acc[4][4], BK=64 ----------------
// 16 MFMA per 8 ds_read_b128 per wave per kk (2x the 8-wave shape's MFMA:LDS ratio).
// Wt is [3072][1024]; Q/K -> [bh][n][hd] bf16; V -> [bh][hd][n] bf16 (fused transpose)
__global__ __launch_bounds__(256) void gemm_kernel(const u16* __restrict__ A,
                                                   const u16* __restrict__ Wt,
                                                   u16* __restrict__ oQ, u16* __restrict__ oK,
                                                   u16* __restrict__ oV) {
  __shared__ u16 Als[128 * 64];
  __shared__ u16 Bls[128 * 64];
  int m0 = blockIdx.y * 128, n0 = blockIdx.x * 128;
  int tid = threadIdx.x;
  int lane = tid & 63, w = tid >> 6;   // 4 waves
  int wm = w >> 1, wn = w & 1;         // 2 x 2 wave grid: 64x64 output each
  int lr = lane & 15, lg = lane >> 4;

  // staging: 1024 slots of 16B per matrix; thread stages slots tid + j*256 (j=0..3).
  // row = s>>3, chunk = s&7; LDS linear at slot*16B; swizzle folded into SOURCE chunk.
  const u16* gA[4]; const u16* gB[4]; u16* lA[4]; u16* lB[4];
#pragma unroll
  for (int j = 0; j < 4; j++) {
    int s = tid + j * 256;
    int row = s >> 3, ch = s & 7;
    int scol = (ch ^ (row & 7)) * 8;
    gA[j] = &A [(size_t)(m0 + row) * DD + scol];
    gB[j] = &Wt[(size_t)(n0 + row) * DD + scol];
    lA[j] = &Als[s * 8];
    lB[j] = &Bls[s * 8];
  }

  f32x4_t acc[4][4];
#pragma unroll
  for (int i = 0; i < 4; i++)
#pragma unroll
    for (int j = 0; j < 4; j++) acc[i][j] = (f32x4_t){0.f, 0.f, 0.f, 0.f};

  for (int kt = 0; kt < DD; kt += 64) {
    __syncthreads();
#pragma unroll
    for (int j = 0; j < 4; j++) {
      async_copy16(gA[j] + kt, lA[j]);
      async_copy16(gB[j] + kt, lB[j]);
    }
    __syncthreads();
#pragma unroll
    for (int kk = 0; kk < 2; kk++) {
      bf16x8_t af[4], bfv[4];
#pragma unroll
      for (int mi = 0; mi < 4; mi++) {
        int row = wm * 64 + mi * 16 + lr;
        int boff = (row * 128 + kk * 64 + lg * 16) ^ ((row & 7) << 4);
        af[mi] = *(const bf16x8_t*)((const char*)Als + boff);
      }
#pragma unroll
      for (int ni = 0; ni < 4; ni++) {
        int row = wn * 64 + ni * 16 + lr;
        int boff = (row * 128 + kk * 64 + lg * 16) ^ ((row & 7) << 4);
        bfv[ni] = *(const bf16x8_t*)((const char*)Bls + boff);
      }
#pragma unroll
      for (int mi = 0; mi < 4; mi++)
#pragma unroll
        for (int ni = 0; ni < 4; ni++)
          acc[mi][ni] = __builtin_amdgcn_mfma_f32_16x16x32_bf16(af[mi], bfv[ni], acc[mi][ni], 0, 0, 0);
    }
  }

  int which = n0 >> 10;
  int nl0 = n0 & 1023;
  if (which == 2) {
    // V: write transposed [bh][hd][n] -- 4 consecutive n per thread = packed 8B store
#pragma unroll
    for (int mi = 0; mi < 4; mi++)
#pragma unroll
      for (int ni = 0; ni < 4; ni++) {
        int gcol = nl0 + wn * 64 + ni * 16 + lr;
        int h = gcol >> 6, hd = gcol & 63;
        int grow0 = m0 + wm * 64 + mi * 16 + lg * 4;
        int b = grow0 >> 11, n = grow0 & (NN - 1);
        ushort4 o4;
        o4.x = f2bf(acc[mi][ni][0]);
        o4.y = f2bf(acc[mi][ni][1]);
        o4.z = f2bf(acc[mi][ni][2]);
        o4.w = f2bf(acc[mi][ni][3]);
        *(ushort4*)&oV[((size_t)(b * HH + h) * HDD + hd) * NN + n] = o4;
      }
  } else {
    u16* outp = which == 0 ? oQ : oK;
#pragma unroll
    for (int mi = 0; mi < 4; mi++)
#pragma unroll
      for (int ni = 0; ni < 4; ni++) {
        int gcol = nl0 + wn * 64 + ni * 16 + lr;
        int h = gcol >> 6, hd = gcol & 63;
#pragma unroll
        for (int r = 0; r < 4; r++) {
          int grow = m0 + wm * 64 + mi * 16 + lg * 4 + r;
          int b = grow >> 11, n = grow & (NN - 1);
          outp[((size_t)(b * HH + h) * NN + n) * HDD + hd] = f2bf(acc[mi][ni][r]);
        }
      }
  }
}

// ---------------- out GEMM 128x64 tile, BK=64, grid 512 = 2 blocks/CU ----------------
__global__ __launch_bounds__(512, 4) void gemm_out_kernel(const u16* __restrict__ A,
                                                          const u16* __restrict__ Wt,
                                                          float* __restrict__ oF) {
  __shared__ u16 Als[128 * 64];
  __shared__ u16 Bls[64 * 64];
  int m0 = blockIdx.y * 128, n0 = blockIdx.x * 64;
  int tid = threadIdx.x;
  int lane = tid & 63, w = tid >> 6;
  int wm = w >> 2, wn = w & 3;
  int lr = lane & 15, lg = lane >> 4;

  const u16* gA[2]; u16* lA[2];
#pragma unroll
  for (int j = 0; j < 2; j++) {
    int s = tid + j * 512;
    int row = s >> 3, ch = s & 7;
    int scol = (ch ^ (row & 7)) * 8;
    gA[j] = &A[(size_t)(m0 + row) * DD + scol];
    lA[j] = &Als[s * 8];
  }
  int rowb = tid >> 3, chb = tid & 7;
  const u16* gB = &Wt[(size_t)(n0 + rowb) * DD + ((chb ^ (rowb & 7)) * 8)];
  u16* lB = &Bls[tid * 8];

  f32x4_t acc[4];
#pragma unroll
  for (int i = 0; i < 4; i++) acc[i] = (f32x4_t){0.f, 0.f, 0.f, 0.f};

  for (int kt = 0; kt < DD; kt += 64) {
    __syncthreads();
#pragma unroll
    for (int j = 0; j < 2; j++) async_copy16(gA[j] + kt, lA[j]);
    async_copy16(gB + kt, lB);
    __syncthreads();
#pragma unroll
    for (int kk = 0; kk < 2; kk++) {
      bf16x8_t af[4], bf1;
#pragma unroll
      for (int mi = 0; mi < 4; mi++) {
        int row = wm * 64 + mi * 16 + lr;
        int boff = (row * 128 + kk * 64 + lg * 16) ^ ((row & 7) << 4);
        af[mi] = *(const bf16x8_t*)((const char*)Als + boff);
      }
      {
        int row = wn * 16 + lr;
        int boff = (row * 128 + kk * 64 + lg * 16) ^ ((row & 7) << 4);
        bf1 = *(const bf16x8_t*)((const char*)Bls + boff);
      }
#pragma unroll
      for (int mi = 0; mi < 4; mi++)
        acc[mi] = __builtin_amdgcn_mfma_f32_16x16x32_bf16(af[mi], bf1, acc[mi], 0, 0, 0);
    }
  }

#pragma unroll
  for (int mi = 0; mi < 4; mi++) {
    int gcol = n0 + wn * 16 + lr;
#pragma unroll
    for (int r = 0; r < 4; r++) {
      int grow = m0 + wm * 64 + mi * 16 + lg * 4 + r;
      oF[(size_t)grow * DD + gcol] = acc[mi][r];
    }
  }
}

// ---------------- flash attention (r19 frozen): KVBLK=128, peeled diagonal, hoisted LDS addressing ----------------
__global__ __launch_bounds__(256) void attn_kernel(const u16* __restrict__ Q,
                                                   const u16* __restrict__ K,
                                                   const u16* __restrict__ Vt,
                                                   const float* __restrict__ cw,
                                                   u16* __restrict__ O) {
  __shared__ u16 Kls[2][KVBLK * 64];   // [128 kv rows][64 hd], 16KB each
  __shared__ u16 Vls[2][64 * KVBLK];   // [64 hd][128 kv], 16KB each
  int flat = blockIdx.y * gridDim.x + blockIdx.x;  // grid (16, 32) = 512
  int swz = (flat & 7) * 64 + (flat >> 3);         // bijective, bh-contiguous per XCD
  int pidx = swz & 15, bh = swz >> 4;
  int tid = threadIdx.x;
  int lane = tid & 63, w = tid >> 6;
  int lr = lane & 15, lg = lane >> 4;
  const u16* Qh = Q + (size_t)bh * NN * HDD;
  const u16* Kh = K + (size_t)bh * NN * HDD;
  const u16* Vh = Vt + (size_t)bh * HDD * NN;
  const float* ch = cw + bh * NN;   // pre-scaled by log2e
  int b = bh >> 4, h = bh & 15;

  const float SCL = 0.125f * LOG2E;

  // per-lane swizzled sub-row offsets (bits 0-7), disjoint from row/f components
  int msk = (lr & 7) << 4;
  int sw0 = (0 * 64 + lg * 16) ^ msk;
  int sw1 = (1 * 64 + lg * 16) ^ msk;
  int sw2 = (2 * 64 + lg * 16) ^ msk;
  int sw3 = (3 * 64 + lg * 16) ^ msk;

  const u16* gk[4]; const u16* gv[4];
#pragma unroll
  for (int j = 0; j < 4; j++) {
    int s = tid + j * 256;
    int kr = s >> 3, kc = s & 7;
    gk[j] = &Kh[(size_t)kr * HDD + ((kc ^ (kr & 7)) * 8)];
    int vr = s >> 4, vc = s & 15;
    gv[j] = &Vh[(size_t)vr * NN + ((vc ^ (vr & 7)) * 8)];
  }

  for (int which = 0; which < 2; which++) {
    int tile = which == 0 ? (31 - pidx) : pidx;
    int qb = tile * QBLK + w * 16;
    int iq = qb + lr;  // this lane's q-row

    bf16x8_t qf[2];
#pragma unroll
    for (int s = 0; s < 2; s++)
      qf[s] = *(const bf16x8_t*)&Qh[(size_t)iq * HDD + s * 32 + lg * 8];
    float cq = ch[iq];

    float lsum = 0.f;
    f32x4_t oacc[4];
#pragma unroll
    for (int fn = 0; fn < 4; fn++) oacc[fn] = (f32x4_t){0.f, 0.f, 0.f, 0.f};

    int nt = (tile >> 1) + 1;

    // prologue: stage kv tile 0 into buffer 0
#pragma unroll
    for (int j = 0; j < 4; j++) {
      int s = tid + j * 256;
      async_copy16(gk[j], &Kls[0][s * 8]);
      async_copy16(gv[j], &Vls[0][s * 8]);
    }
    __syncthreads();

    auto body = [&](int kvt, int bufc, bool masked) {
      int kv0 = kvt * KVBLK;
      const char* kp0 = (const char*)Kls[bufc] + lr * 128 + sw0;
      const char* kp1 = (const char*)Kls[bufc] + lr * 128 + sw1;
      const char* vp0 = (const char*)Vls[bufc] + lr * 256 + sw0;
      const char* vp1 = (const char*)Vls[bufc] + lr * 256 + sw1;
      const char* vp2 = (const char*)Vls[bufc] + lr * 256 + sw2;
      const char* vp3 = (const char*)Vls[bufc] + lr * 256 + sw3;
      float4 ckv[8];
#pragma unroll
      for (int f = 0; f < 8; f++)
        ckv[f] = *(const float4*)&ch[kv0 + f * 16 + lg * 4];

      f32x4_t sacc[8];
#pragma unroll
      for (int f = 0; f < 8; f++) sacc[f] = (f32x4_t){0.f, 0.f, 0.f, 0.f};
      __builtin_amdgcn_s_setprio(1);
#pragma unroll
      for (int f = 0; f < 8; f++) {
        bf16x8_t k0 = *(const bf16x8_t*)(kp0 + f * 2048);
        bf16x8_t k1 = *(const bf16x8_t*)(kp1 + f * 2048);
        sacc[f] = __builtin_amdgcn_mfma_f32_16x16x32_bf16(k0, qf[0], sacc[f], 0, 0, 0);
        sacc[f] = __builtin_amdgcn_mfma_f32_16x16x32_bf16(k1, qf[1], sacc[f], 0, 0, 0);
      }
      __builtin_amdgcn_s_setprio(0);

      float pv[8][4];
#pragma unroll
      for (int f = 0; f < 8; f++) {
        const float* ckp = &ckv[f].x;
#pragma unroll
        for (int r = 0; r < 4; r++) {
          float val = fmaf(sacc[f][r], SCL, cq - ckp[r]);
          float e = exp2_raw(val);
          if (masked && (kv0 + f * 16 + lg * 4 + r) > iq) e = 0.f;
          pv[f][r] = e; lsum += e;
        }
      }

      bf16x8_t pa[4];
#pragma unroll
      for (int s = 0; s < 4; s++) {
        uint32_t x0 = packbf2(pv[2 * s][0], pv[2 * s][1]);
        uint32_t x1 = packbf2(pv[2 * s][2], pv[2 * s][3]);
        uint32_t y0 = packbf2(pv[2 * s + 1][0], pv[2 * s + 1][1]);
        uint32_t y1 = packbf2(pv[2 * s + 1][2], pv[2 * s + 1][3]);
        asm volatile("v_permlane32_swap_b32 %0, %1" : "+v"(x0), "+v"(y0));
        asm volatile("v_permlane32_swap_b32 %0, %1" : "+v"(x1), "+v"(y1));
        asm volatile("v_permlane16_swap_b32 %0, %1" : "+v"(x0), "+v"(y0));
        asm volatile("v_permlane16_swap_b32 %0, %1" : "+v"(x1), "+v"(y1));
        union { uint32_t u[4]; bf16x8_t v; } pk;
        pk.u[0] = x0; pk.u[1] = x1; pk.u[2] = y0; pk.u[3] = y1;
        pa[s] = pk.v;
      }

      __builtin_amdgcn_s_setprio(1);
#pragma unroll
      for (int fn = 0; fn < 4; fn++) {
        bf16x8_t v0 = *(const bf16x8_t*)(vp0 + fn * 4096);
        bf16x8_t v1 = *(const bf16x8_t*)(vp1 + fn * 4096);
        bf16x8_t v2 = *(const bf16x8_t*)(vp2 + fn * 4096);
        bf16x8_t v3 = *(const bf16x8_t*)(vp3 + fn * 4096);
        oacc[fn] = __builtin_amdgcn_mfma_f32_16x16x32_bf16(v0, pa[0], oacc[fn], 0, 0, 0);
        oacc[fn] = __builtin_amdgcn_mfma_f32_16x16x32_bf16(v1, pa[1], oacc[fn], 0, 0, 0);
        oacc[fn] = __builtin_amdgcn_mfma_f32_16x16x32_bf16(v2, pa[2], oacc[fn], 0, 0, 0);
        oacc[fn] = __builtin_amdgcn_mfma_f32_16x16x32_bf16(v3, pa[3], oacc[fn], 0, 0, 0);
      }
      __builtin_amdgcn_s_setprio(0);
    };

    int cur = 0;
    for (int kvt = 0; kvt < nt - 1; kvt++) {
      int nb = cur ^ 1;
      size_t kvn = (size_t)(kvt + 1) * KVBLK;
#pragma unroll
      for (int j = 0; j < 4; j++) {
        int s = tid + j * 256;
        async_copy16(gk[j] + kvn * HDD, &Kls[nb][s * 8]);
        async_copy16(gv[j] + kvn, &Vls[nb][s * 8]);
      }
      body(kvt, cur, false);   // hot path: no mask ops
      __syncthreads();
      cur ^= 1;
    }
    body(nt - 1, cur, true);   // peeled diagonal iteration
    __syncthreads();

    // l-reduce over the 4 lanes sharing lr
    lsum += __shfl_xor(lsum, 16, 64);
    lsum += __shfl_xor(lsum, 32, 64);
    float rinv = 1.0f / lsum;

    u16* orow = O + ((size_t)(b * NN + iq)) * DD + h * HDD;
#pragma unroll
    for (int fn = 0; fn < 4; fn++) {
      ushort4 o4;
      o4.x = f2bf(oacc[fn][0] * rinv);
      o4.y = f2bf(oacc[fn][1] * rinv);
      o4.z = f2bf(oacc[fn][2] * rinv);
      o4.w = f2bf(oacc[fn][3] * rinv);
      *(ushort4*)&orow[fn * 16 + lg * 4] = o4;
    }
  }
}

extern "C" void kernel_launch(void* const* d_in, const int* in_sizes, int n_in,
                              void* d_out, int out_size, void* d_ws, size_t ws_size,
                              hipStream_t stream) {
  const float* x  = (const float*)d_in[0];
  const float* Wq = (const float*)d_in[1];
  const float* Wk = (const float*)d_in[2];
  const float* Wv = (const float*)d_in[3];
  const float* Wo = (const float*)d_in[4];
  const float* Wf = (const float*)d_in[5];
  float* out = (float*)d_out;
  char* ws = (char*)d_ws;
  const size_t MB = 1024 * 1024;
  u16* x_bf  = (u16*)(ws + 0);        // 8 MB
  u16* WqkvT = (u16*)(ws + 8 * MB);   // 6 MB: WqT | WkT | WvT contiguous [3072][1024]; WoT follows
  u16* Qw    = (u16*)(ws + 16 * MB);  // 8 MB [bh][n][hd]
  u16* Kw    = (u16*)(ws + 24 * MB);  // 8 MB
  u16* Vw    = (u16*)(ws + 32 * MB);  // 8 MB [bh][hd][n] (written transposed by gemm)
  u16* Ow    = (u16*)(ws + 40 * MB);  // 8 MB [b n d]
  float* lf  = (float*)(ws + 48 * MB);            // 256 KB
  float* cwp = (float*)(ws + 48 * MB + 262144);   // 256 KB (pre-scaled by log2e)

  // fused prep: logf+cast (4096 blocks) || weight transpose (1024 blocks)
  prep_kernel<<<5120, 256, 0, stream>>>(x, Wf, lf, x_bf, Wq, Wk, Wv, Wo, WqkvT);
  cumsum_kernel<<<32, 64, 0, stream>>>(lf, cwp);
  // fused QKV GEMM (m97 4-wave shape): N = 3072; V written directly transposed
  gemm_kernel<<<dim3(24, 32), 256, 0, stream>>>(x_bf, WqkvT, Qw, Kw, Vw);
  attn_kernel<<<dim3(16, 32), 256, 0, stream>>>(Qw, Kw, Vw, cwp, Ow);
  gemm_out_kernel<<<dim3(16, 32), 512, 0, stream>>>(Ow, WqkvT + (size_t)3 * DD * DD, out);
}

// Round 21
// 118.452 us; speedup vs baseline: 1.0381x; 1.0381x over previous
//
#include <hip/hip_runtime.h>
#include <hip/hip_bf16.h>
#include <stdint.h>

#define NN 2048
#define DD 1024
#define HH 16
#define HDD 64
#define QBLK 64
#define KVBLK 128

typedef unsigned short u16;
typedef __attribute__((ext_vector_type(8))) __bf16 bf16x8_t;
typedef __attribute__((ext_vector_type(4))) float f32x4_t;

#define LOG2E 1.44269504f

static __device__ __forceinline__ u16 f2bf(float f) {
  union { float f; uint32_t u; } v; v.f = f;
  uint32_t r = v.u + 0x7FFFu + ((v.u >> 16) & 1u);
  return (u16)(r >> 16);
}

static __device__ __forceinline__ uint32_t packbf2(float a, float b) {
  __hip_bfloat162 h2 = __float22bfloat162_rn(make_float2(a, b));
  union { __hip_bfloat162 hh; uint32_t u; } cvt; cvt.hh = h2;
  return cvt.u;
}

// raw v_exp_f32: computes 2^x in ONE instruction (no libm slow path, no ln2 mul)
static __device__ __forceinline__ float exp2_raw(float x) {
  float r;
  asm("v_exp_f32 %0, %1" : "=v"(r) : "v"(x));
  return r;
}

// async global->LDS, 16B per lane. LDS dest must be wave-uniform base + lane*16.
static __device__ __forceinline__ void async_copy16(const void* g, void* l) {
  __builtin_amdgcn_global_load_lds((const __attribute__((address_space(1))) void*)g,
                                   (__attribute__((address_space(3))) void*)l, 16, 0, 0);
}

// ---------------- fused prep: logf (blocks 0..4095) + weight transpose (blocks 4096..5119) ----------------
__global__ void prep_kernel(const float* __restrict__ x, const float* __restrict__ Wf,
                            float* __restrict__ lf, u16* __restrict__ xb,
                            const float* __restrict__ W0, const float* __restrict__ W1,
                            const float* __restrict__ W2, const float* __restrict__ W3,
                            u16* __restrict__ Wt) {
  __shared__ float xs[DD];
  __shared__ float part[16][17];
  __shared__ float tile[64][65];
  int t = threadIdx.x;  // 256
  if (blockIdx.x < 4096) {
    int row = blockIdx.x;   // b*N + n
    float4 v = *(const float4*)&x[(size_t)row * DD + t * 4];
    *(float4*)&xs[t * 4] = v;
    ushort4 o;
    o.x = f2bf(v.x); o.y = f2bf(v.y); o.z = f2bf(v.z); o.w = f2bf(v.w);
    *(ushort4*)&xb[(size_t)row * DD + t * 4] = o;
    __syncthreads();
    int h = t & 15, chunk = t >> 4;
    float s = 0.f;
#pragma unroll 8
    for (int e = 0; e < 64; e++)
      s += xs[chunk * 64 + e] * Wf[(chunk * 64 + e) * HH + h];
    part[chunk][h] = s;
    __syncthreads();
    if (t < 16) {
      float z = 0.f;
#pragma unroll
      for (int i = 0; i < 16; i++) z += part[i][t];
      float ls = fminf(z, 0.f) - log1pf(__expf(-fabsf(z)));
      int b = row >> 11, n = row & (NN - 1);
      lf[(b * HH + t) * NN + n] = ls;
    }
  } else {
    int bid = blockIdx.x - 4096;
    int wq = bid >> 8;  // which weight
    const float* W = wq == 0 ? W0 : wq == 1 ? W1 : wq == 2 ? W2 : W3;
    u16* out = Wt + (size_t)wq * DD * DD;
    int bx = bid & 15;          // n tile
    int by = (bid >> 4) & 15;   // k tile
    int c = t & 63, r4 = t >> 6;
#pragma unroll
    for (int i = 0; i < 16; i++) {
      int row = i * 4 + r4;
      tile[row][c] = W[(by * 64 + row) * DD + bx * 64 + c];
    }
    __syncthreads();
#pragma unroll
    for (int i = 0; i < 16; i++) {
      int row = i * 4 + r4;
      out[(bx * 64 + row) * DD + by * 64 + c] = f2bf(tile[c][row]);
    }
  }
}

// ---------------- cumsum over n per (b,h): float4/lane; OUTPUT PRE-SCALED by log2(e) ----------------
__global__ void cumsum_kernel(const float* __restrict__ lf, float* __restrict__ c) {
  int bh = blockIdx.x;
  int lane = threadIdx.x;  // 64
  const float* in = lf + bh * NN;
  float* out = c + bh * NN;
  float carry = 0.f;
  for (int t0 = 0; t0 < NN; t0 += 256) {
    float4 v = *(const float4*)&in[t0 + lane * 4];
    float s1 = v.x + v.y, s2 = s1 + v.z, s3 = s2 + v.w;
    float incl = s3;
#pragma unroll
    for (int off = 1; off < 64; off <<= 1) {
      float u = __shfl_up(incl, off, 64);
      if (lane >= off) incl += u;
    }
    float excl = incl - s3 + carry;
    float4 o;
    o.x = (excl + v.x) * LOG2E; o.y = (excl + s1) * LOG2E;
    o.z = (excl + s2) * LOG2E; o.w = (excl + s3) * LOG2E;
    *(float4*)&out[t0 + lane * 4] = o;
    carry = __shfl(incl, 63, 64) + carry;
  }
}

// ---------------- QKV GEMM 128x128 tile, BK=64, swizzled LDS, 512 threads (8 waves, 2x4) ----------------
// Wt is [3072][1024]; Q/K -> [bh][n][hd] bf16; V -> [bh][hd][n] bf16 (fused transpose)
__global__ __launch_bounds__(512, 4) void gemm_kernel(const u16* __restrict__ A,
                                                      const u16* __restrict__ Wt,
                                                      u16* __restrict__ oQ, u16* __restrict__ oK,
                                                      u16* __restrict__ oV) {
  __shared__ u16 Als[128 * 64];
  __shared__ u16 Bls[128 * 64];
  int m0 = blockIdx.y * 128, n0 = blockIdx.x * 128;
  int tid = threadIdx.x;
  int lane = tid & 63, w = tid >> 6;   // 8 waves
  int wm = w >> 2, wn = w & 3;         // 2 x 4 wave grid: 64 rows x 32 cols each
  int lr = lane & 15, lg = lane >> 4;

  const u16* gA[2]; const u16* gB[2]; u16* lA[2]; u16* lB[2];
#pragma unroll
  for (int j = 0; j < 2; j++) {
    int s = tid + j * 512;
    int row = s >> 3, ch = s & 7;
    int scol = (ch ^ (row & 7)) * 8;
    gA[j] = &A [(size_t)(m0 + row) * DD + scol];
    gB[j] = &Wt[(size_t)(n0 + row) * DD + scol];
    lA[j] = &Als[s * 8];
    lB[j] = &Bls[s * 8];
  }

  f32x4_t acc[4][2];
#pragma unroll
  for (int i = 0; i < 4; i++)
#pragma unroll
    for (int j = 0; j < 2; j++) acc[i][j] = (f32x4_t){0.f, 0.f, 0.f, 0.f};

  for (int kt = 0; kt < DD; kt += 64) {
    __syncthreads();
#pragma unroll
    for (int j = 0; j < 2; j++) {
      async_copy16(gA[j] + kt, lA[j]);
      async_copy16(gB[j] + kt, lB[j]);
    }
    __syncthreads();
#pragma unroll
    for (int kk = 0; kk < 2; kk++) {
      bf16x8_t af[4], bfv[2];
#pragma unroll
      for (int mi = 0; mi < 4; mi++) {
        int row = wm * 64 + mi * 16 + lr;
        int boff = (row * 128 + kk * 64 + lg * 16) ^ ((row & 7) << 4);
        af[mi] = *(const bf16x8_t*)((const char*)Als + boff);
      }
#pragma unroll
      for (int ni = 0; ni < 2; ni++) {
        int row = wn * 32 + ni * 16 + lr;
        int boff = (row * 128 + kk * 64 + lg * 16) ^ ((row & 7) << 4);
        bfv[ni] = *(const bf16x8_t*)((const char*)Bls + boff);
      }
#pragma unroll
      for (int mi = 0; mi < 4; mi++)
#pragma unroll
        for (int ni = 0; ni < 2; ni++)
          acc[mi][ni] = __builtin_amdgcn_mfma_f32_16x16x32_bf16(af[mi], bfv[ni], acc[mi][ni], 0, 0, 0);
    }
  }

  int which = n0 >> 10;
  int nl0 = n0 & 1023;
  if (which == 2) {
    // V: write transposed [bh][hd][n] -- 4 consecutive n per thread = packed 8B store
#pragma unroll
    for (int mi = 0; mi < 4; mi++)
#pragma unroll
      for (int ni = 0; ni < 2; ni++) {
        int gcol = nl0 + wn * 32 + ni * 16 + lr;
        int h = gcol >> 6, hd = gcol & 63;
        int grow0 = m0 + wm * 64 + mi * 16 + lg * 4;
        int b = grow0 >> 11, n = grow0 & (NN - 1);
        ushort4 o4;
        o4.x = f2bf(acc[mi][ni][0]);
        o4.y = f2bf(acc[mi][ni][1]);
        o4.z = f2bf(acc[mi][ni][2]);
        o4.w = f2bf(acc[mi][ni][3]);
        *(ushort4*)&oV[((size_t)(b * HH + h) * HDD + hd) * NN + n] = o4;
      }
  } else {
    u16* outp = which == 0 ? oQ : oK;
#pragma unroll
    for (int mi = 0; mi < 4; mi++)
#pragma unroll
      for (int ni = 0; ni < 2; ni++) {
        int gcol = nl0 + wn * 32 + ni * 16 + lr;
        int h = gcol >> 6, hd = gcol & 63;
#pragma unroll
        for (int r = 0; r < 4; r++) {
          int grow = m0 + wm * 64 + mi * 16 + lg * 4 + r;
          int b = grow >> 11, n = grow & (NN - 1);
          outp[((size_t)(b * HH + h) * NN + n) * HDD + hd] = f2bf(acc[mi][ni][r]);
        }
      }
  }
}

// ---------------- out GEMM 128x64 tile, BK=64, grid 512 = 2 blocks/CU (overlap barrier stalls) ----------------
__global__ __launch_bounds__(512, 4) void gemm_out_kernel(const u16* __restrict__ A,
                                                          const u16* __restrict__ Wt,
                                                          float* __restrict__ oF) {
  __shared__ u16 Als[128 * 64];
  __shared__ u16 Bls[64 * 64];
  int m0 = blockIdx.y * 128, n0 = blockIdx.x * 64;
  int tid = threadIdx.x;
  int lane = tid & 63, w = tid >> 6;   // 8 waves
  int wm = w >> 2, wn = w & 3;         // 2 x 4 wave grid: 64 rows x 16 cols each
  int lr = lane & 15, lg = lane >> 4;

  const u16* gA[2]; u16* lA[2];
#pragma unroll
  for (int j = 0; j < 2; j++) {
    int s = tid + j * 512;
    int row = s >> 3, ch = s & 7;
    int scol = (ch ^ (row & 7)) * 8;
    gA[j] = &A[(size_t)(m0 + row) * DD + scol];
    lA[j] = &Als[s * 8];
  }
  int rowb = tid >> 3, chb = tid & 7;
  const u16* gB = &Wt[(size_t)(n0 + rowb) * DD + ((chb ^ (rowb & 7)) * 8)];
  u16* lB = &Bls[tid * 8];

  f32x4_t acc[4];
#pragma unroll
  for (int i = 0; i < 4; i++) acc[i] = (f32x4_t){0.f, 0.f, 0.f, 0.f};

  for (int kt = 0; kt < DD; kt += 64) {
    __syncthreads();
#pragma unroll
    for (int j = 0; j < 2; j++) async_copy16(gA[j] + kt, lA[j]);
    async_copy16(gB + kt, lB);
    __syncthreads();
#pragma unroll
    for (int kk = 0; kk < 2; kk++) {
      bf16x8_t af[4], bf1;
#pragma unroll
      for (int mi = 0; mi < 4; mi++) {
        int row = wm * 64 + mi * 16 + lr;
        int boff = (row * 128 + kk * 64 + lg * 16) ^ ((row & 7) << 4);
        af[mi] = *(const bf16x8_t*)((const char*)Als + boff);
      }
      {
        int row = wn * 16 + lr;
        int boff = (row * 128 + kk * 64 + lg * 16) ^ ((row & 7) << 4);
        bf1 = *(const bf16x8_t*)((const char*)Bls + boff);
      }
#pragma unroll
      for (int mi = 0; mi < 4; mi++)
        acc[mi] = __builtin_amdgcn_mfma_f32_16x16x32_bf16(af[mi], bf1, acc[mi], 0, 0, 0);
    }
  }

#pragma unroll
  for (int mi = 0; mi < 4; mi++) {
    int gcol = n0 + wn * 16 + lr;
#pragma unroll
    for (int r = 0; r < 4; r++) {
      int grow = m0 + wm * 64 + mi * 16 + lg * 4 + r;
      oF[(size_t)grow * DD + gcol] = acc[mi][r];
    }
  }
}

// ---------------- flash attention: KVBLK=128 (half the barriers), raw v_exp softmax ----------------
// Sequential paired q-tiles (31-p then p); per tile nt = (tile>>1)+1 kv tiles of 128
// (UNIFORM pair total = 17 iters for every p). Even tiles' last kv tile overhangs <=64
// cols past the diagonal -- all reads in-bounds (<=2048), masked via jj>iq AFTER exp
// (garbage-safe). Double-buffered global_load_lds staging (8x16B/thread per tile);
// exp2-domain softmax: cw pre-scaled by log2e, SCL=0.125*log2e, raw v_exp_f32.
__global__ __launch_bounds__(256) void attn_kernel(const u16* __restrict__ Q,
                                                   const u16* __restrict__ K,
                                                   const u16* __restrict__ Vt,
                                                   const float* __restrict__ cw,
                                                   u16* __restrict__ O) {
  __shared__ u16 Kls[2][KVBLK * 64];   // [128 kv rows][64 hd], 16KB each
  __shared__ u16 Vls[2][64 * KVBLK];   // [64 hd][128 kv], 16KB each
  int flat = blockIdx.y * gridDim.x + blockIdx.x;  // grid (16, 32) = 512
  int swz = (flat & 7) * 64 + (flat >> 3);         // bijective, bh-contiguous per XCD
  int pidx = swz & 15, bh = swz >> 4;
  int tid = threadIdx.x;
  int lane = tid & 63, w = tid >> 6;
  int lr = lane & 15, lg = lane >> 4;
  const u16* Qh = Q + (size_t)bh * NN * HDD;
  const u16* Kh = K + (size_t)bh * NN * HDD;
  const u16* Vh = Vt + (size_t)bh * HDD * NN;
  const float* ch = cw + bh * NN;   // pre-scaled by log2e
  int b = bh >> 4, h = bh & 15;

  const float SCL = 0.125f * LOG2E;

  // staging: K tile = 1024 slots of 16B (row=s>>3, chunk=s&7); V tile = 1024 slots
  // (row=s>>4, chunk=s&15). Thread stages slots tid+j*256, j=0..3. LDS linear at
  // slot*16B; swizzle folded into SOURCE chunk: chunk ^ (row&7).
  const u16* gk[4]; const u16* gv[4];
#pragma unroll
  for (int j = 0; j < 4; j++) {
    int s = tid + j * 256;
    int kr = s >> 3, kc = s & 7;
    gk[j] = &Kh[(size_t)kr * HDD + ((kc ^ (kr & 7)) * 8)];
    int vr = s >> 4, vc = s & 15;
    gv[j] = &Vh[(size_t)vr * NN + ((vc ^ (vr & 7)) * 8)];
  }

  for (int which = 0; which < 2; which++) {
    int tile = which == 0 ? (31 - pidx) : pidx;
    int qb = tile * QBLK + w * 16;
    int iq = qb + lr;  // this lane's q-row

    bf16x8_t qf[2];
#pragma unroll
    for (int s = 0; s < 2; s++)
      qf[s] = *(const bf16x8_t*)&Qh[(size_t)iq * HDD + s * 32 + lg * 8];
    float cq = ch[iq];

    float lsum = 0.f;
    f32x4_t oacc[4];
#pragma unroll
    for (int fn = 0; fn < 4; fn++) oacc[fn] = (f32x4_t){0.f, 0.f, 0.f, 0.f};

    int nt = (tile >> 1) + 1;

    // prologue: stage kv tile 0 into buffer 0
#pragma unroll
    for (int j = 0; j < 4; j++) {
      int s = tid + j * 256;
      async_copy16(gk[j], &Kls[0][s * 8]);
      async_copy16(gv[j], &Vls[0][s * 8]);
    }
    __syncthreads();

    int cur = 0;
    for (int kvt = 0; kvt < nt; kvt++) {
      // stage next tile into the other buffer BEFORE computing this one
      if (kvt + 1 < nt) {
        size_t kvn = (size_t)(kvt + 1) * KVBLK;
        int nb = cur ^ 1;
#pragma unroll
        for (int j = 0; j < 4; j++) {
          int s = tid + j * 256;
          async_copy16(gk[j] + kvn * HDD, &Kls[nb][s * 8]);
          async_copy16(gv[j] + kvn, &Vls[nb][s * 8]);
        }
      }
      int kv0 = kvt * KVBLK;
      const u16* Kb = Kls[cur];
      const u16* Vb = Vls[cur];
      float4 ckv[8];
#pragma unroll
      for (int f = 0; f < 8; f++)
        ckv[f] = *(const float4*)&ch[kv0 + f * 16 + lg * 4];

      // S^T = K . Q^T : lane holds col i=lr, rows j = kv0 + f*16 + lg*4 + r  (f=0..7)
      f32x4_t sacc[8];
#pragma unroll
      for (int f = 0; f < 8; f++) sacc[f] = (f32x4_t){0.f, 0.f, 0.f, 0.f};
      __builtin_amdgcn_s_setprio(1);
#pragma unroll
      for (int f = 0; f < 8; f++) {
        int row = f * 16 + lr;
#pragma unroll
        for (int s = 0; s < 2; s++) {
          int boff = (row * 128 + s * 64 + lg * 16) ^ ((row & 7) << 4);
          bf16x8_t kf = *(const bf16x8_t*)((const char*)Kb + boff);
          sacc[f] = __builtin_amdgcn_mfma_f32_16x16x32_bf16(kf, qf[s], sacc[f], 0, 0, 0);
        }
      }
      __builtin_amdgcn_s_setprio(0);

      // fixed-max softmax, exp2 domain: e = 2^(s*SCL + cq - ck); mask AFTER exp
      bool diag = (kvt == nt - 1);
      float pv[8][4];
#pragma unroll
      for (int f = 0; f < 8; f++) {
        const float* ckp = &ckv[f].x;
#pragma unroll
        for (int r = 0; r < 4; r++) {
          float val = fmaf(sacc[f][r], SCL, cq - ckp[r]);
          float e = exp2_raw(val);
          if (diag && (kv0 + f * 16 + lg * 4 + r) > iq) e = 0.f;
          pv[f][r] = e; lsum += e;
        }
      }

      // pack P quarters to bf16 + permlane network -> 4 B-fragments (s covers kv cols 32s..32s+31)
      bf16x8_t pa[4];
#pragma unroll
      for (int s = 0; s < 4; s++) {
        uint32_t x0 = packbf2(pv[2 * s][0], pv[2 * s][1]);
        uint32_t x1 = packbf2(pv[2 * s][2], pv[2 * s][3]);
        uint32_t y0 = packbf2(pv[2 * s + 1][0], pv[2 * s + 1][1]);
        uint32_t y1 = packbf2(pv[2 * s + 1][2], pv[2 * s + 1][3]);
        asm volatile("v_permlane32_swap_b32 %0, %1" : "+v"(x0), "+v"(y0));
        asm volatile("v_permlane32_swap_b32 %0, %1" : "+v"(x1), "+v"(y1));
        asm volatile("v_permlane16_swap_b32 %0, %1" : "+v"(x0), "+v"(y0));
        asm volatile("v_permlane16_swap_b32 %0, %1" : "+v"(x1), "+v"(y1));
        union { uint32_t u[4]; bf16x8_t v; } pk;
        pk.u[0] = x0; pk.u[1] = x1; pk.u[2] = y0; pk.u[3] = y1;
        pa[s] = pk.v;
      }

      // O^T += V^T . P  (V^T rows are 256B; swizzle on within-row offset only)
      __builtin_amdgcn_s_setprio(1);
#pragma unroll
      for (int fn = 0; fn < 4; fn++) {
        int row = fn * 16 + lr;
#pragma unroll
        for (int s = 0; s < 4; s++) {
          int boff = row * 256 + ((s * 64 + lg * 16) ^ ((row & 7) << 4));
          bf16x8_t vf = *(const bf16x8_t*)((const char*)Vb + boff);
          oacc[fn] = __builtin_amdgcn_mfma_f32_16x16x32_bf16(vf, pa[s], oacc[fn], 0, 0, 0);
        }
      }
      __builtin_amdgcn_s_setprio(0);
      __syncthreads();
      cur ^= 1;
    }

    // l-reduce over the 4 lanes sharing lr
    lsum += __shfl_xor(lsum, 16, 64);
    lsum += __shfl_xor(lsum, 32, 64);
    float rinv = 1.0f / lsum;

    // output: lane's q-row iq, hd = fn*16 + lg*4 + r -> packed 8B stores
    u16* orow = O + ((size_t)(b * NN + iq)) * DD + h * HDD;
#pragma unroll
    for (int fn = 0; fn < 4; fn++) {
      ushort4 o4;
      o4.x = f2bf(oacc[fn][0] * rinv);
      o4.y = f2bf(oacc[fn][1] * rinv);
      o4.z = f2bf(oacc[fn][2] * rinv);
      o4.w = f2bf(oacc[fn][3] * rinv);
      *(ushort4*)&orow[fn * 16 + lg * 4] = o4;
    }
  }
}

extern "C" void kernel_launch(void* const* d_in, const int* in_sizes, int n_in,
                              void* d_out, int out_size, void* d_ws, size_t ws_size,
                              hipStream_t stream) {
  const float* x  = (const float*)d_in[0];
  const float* Wq = (const float*)d_in[1];
  const float* Wk = (const float*)d_in[2];
  const float* Wv = (const float*)d_in[3];
  const float* Wo = (const float*)d_in[4];
  const float* Wf = (const float*)d_in[5];
  float* out = (float*)d_out;
  char* ws = (char*)d_ws;
  const size_t MB = 1024 * 1024;
  u16* x_bf  = (u16*)(ws + 0);        // 8 MB
  u16* WqkvT = (u16*)(ws + 8 * MB);   // 6 MB: WqT | WkT | WvT contiguous [3072][1024]; WoT follows
  u16* Qw    = (u16*)(ws + 16 * MB);  // 8 MB [bh][n][hd]
  u16* Kw    = (u16*)(ws + 24 * MB);  // 8 MB
  u16* Vw    = (u16*)(ws + 32 * MB);  // 8 MB [bh][hd][n] (written transposed by gemm)
  u16* Ow    = (u16*)(ws + 40 * MB);  // 8 MB [b n d]
  float* lf  = (float*)(ws + 48 * MB);            // 256 KB
  float* cwp = (float*)(ws + 48 * MB + 262144);   // 256 KB (pre-scaled by log2e)

  // fused prep: logf+cast (4096 blocks) || weight transpose (1024 blocks)
  prep_kernel<<<5120, 256, 0, stream>>>(x, Wf, lf, x_bf, Wq, Wk, Wv, Wo, WqkvT);
  cumsum_kernel<<<32, 64, 0, stream>>>(lf, cwp);
  // fused QKV GEMM: N = 3072; V written directly transposed
  gemm_kernel<<<dim3(24, 32), 512, 0, stream>>>(x_bf, WqkvT, Qw, Kw, Vw);
  attn_kernel<<<dim3(16, 32), 256, 0, stream>>>(Qw, Kw, Vw, cwp, Ow);
  gemm_out_kernel<<<dim3(16, 32), 512, 0, stream>>>(Ow, WqkvT + (size_t)3 * DD * DD, out);
}

// Round 22
// 117.469 us; speedup vs baseline: 1.0467x; 1.0084x over previous
//
#include <hip/hip_runtime.h>
#include <hip/hip_bf16.h>
#include <stdint.h>

#define NN 2048
#define DD 1024
#define HH 16
#define HDD 64
#define QBLK 64
#define KVBLK 128

typedef unsigned short u16;
typedef __attribute__((ext_vector_type(8))) __bf16 bf16x8_t;
typedef __attribute__((ext_vector_type(4))) float f32x4_t;

#define LOG2E 1.44269504f

static __device__ __forceinline__ u16 f2bf(float f) {
  union { float f; uint32_t u; } v; v.f = f;
  uint32_t r = v.u + 0x7FFFu + ((v.u >> 16) & 1u);
  return (u16)(r >> 16);
}

static __device__ __forceinline__ uint32_t packbf2(float a, float b) {
  __hip_bfloat162 h2 = __float22bfloat162_rn(make_float2(a, b));
  union { __hip_bfloat162 hh; uint32_t u; } cvt; cvt.hh = h2;
  return cvt.u;
}

// raw v_exp_f32: computes 2^x in ONE instruction (no libm slow path, no ln2 mul)
static __device__ __forceinline__ float exp2_raw(float x) {
  float r;
  asm("v_exp_f32 %0, %1" : "=v"(r) : "v"(x));
  return r;
}

// async global->LDS, 16B per lane. LDS dest must be wave-uniform base + lane*16.
static __device__ __forceinline__ void async_copy16(const void* g, void* l) {
  __builtin_amdgcn_global_load_lds((const __attribute__((address_space(1))) void*)g,
                                   (__attribute__((address_space(3))) void*)l, 16, 0, 0);
}

// ---------------- fused prep: logf (blocks 0..4095) + weight transpose (blocks 4096..5119) ----------------
__global__ void prep_kernel(const float* __restrict__ x, const float* __restrict__ Wf,
                            float* __restrict__ lf, u16* __restrict__ xb,
                            const float* __restrict__ W0, const float* __restrict__ W1,
                            const float* __restrict__ W2, const float* __restrict__ W3,
                            u16* __restrict__ Wt) {
  __shared__ float xs[DD];
  __shared__ float part[16][17];
  __shared__ float tile[64][65];
  int t = threadIdx.x;  // 256
  if (blockIdx.x < 4096) {
    int row = blockIdx.x;   // b*N + n
    float4 v = *(const float4*)&x[(size_t)row * DD + t * 4];
    *(float4*)&xs[t * 4] = v;
    ushort4 o;
    o.x = f2bf(v.x); o.y = f2bf(v.y); o.z = f2bf(v.z); o.w = f2bf(v.w);
    *(ushort4*)&xb[(size_t)row * DD + t * 4] = o;
    __syncthreads();
    int h = t & 15, chunk = t >> 4;
    float s = 0.f;
#pragma unroll 8
    for (int e = 0; e < 64; e++)
      s += xs[chunk * 64 + e] * Wf[(chunk * 64 + e) * HH + h];
    part[chunk][h] = s;
    __syncthreads();
    if (t < 16) {
      float z = 0.f;
#pragma unroll
      for (int i = 0; i < 16; i++) z += part[i][t];
      float ls = fminf(z, 0.f) - log1pf(__expf(-fabsf(z)));
      int b = row >> 11, n = row & (NN - 1);
      lf[(b * HH + t) * NN + n] = ls;
    }
  } else {
    int bid = blockIdx.x - 4096;
    int wq = bid >> 8;  // which weight
    const float* W = wq == 0 ? W0 : wq == 1 ? W1 : wq == 2 ? W2 : W3;
    u16* out = Wt + (size_t)wq * DD * DD;
    int bx = bid & 15;          // n tile
    int by = (bid >> 4) & 15;   // k tile
    int c = t & 63, r4 = t >> 6;
#pragma unroll
    for (int i = 0; i < 16; i++) {
      int row = i * 4 + r4;
      tile[row][c] = W[(by * 64 + row) * DD + bx * 64 + c];
    }
    __syncthreads();
#pragma unroll
    for (int i = 0; i < 16; i++) {
      int row = i * 4 + r4;
      out[(bx * 64 + row) * DD + by * 64 + c] = f2bf(tile[c][row]);
    }
  }
}

// ---------------- QKV GEMM (grid 25x32): cols 0..23 = 128x128 GEMM tiles; col 24 = cumsum ----------------
// GEMM: Wt is [3072][1024]; Q/K -> [bh][n][hd] bf16; V -> [bh][hd][n] bf16 (fused transpose).
// Cumsum (col 24, one block per bh, wave 0 only): scan of lf -> cwp, pre-scaled by log2e.
// Shadowed under the 768 fat GEMM blocks -> its serial wall time vanishes.
__global__ __launch_bounds__(512, 4) void gemm_kernel(const u16* __restrict__ A,
                                                      const u16* __restrict__ Wt,
                                                      u16* __restrict__ oQ, u16* __restrict__ oK,
                                                      u16* __restrict__ oV,
                                                      const float* __restrict__ lf,
                                                      float* __restrict__ cwp) {
  if (blockIdx.x == 24) {
    // ---- fused cumsum: bh = blockIdx.y, wave 0 only ----
    if (threadIdx.x < 64) {
      int bh = blockIdx.y;
      int lane = threadIdx.x;
      const float* in = lf + bh * NN;
      float* out = cwp + bh * NN;
      float carry = 0.f;
      for (int t0 = 0; t0 < NN; t0 += 256) {
        float4 v = *(const float4*)&in[t0 + lane * 4];
        float s1 = v.x + v.y, s2 = s1 + v.z, s3 = s2 + v.w;
        float incl = s3;
#pragma unroll
        for (int off = 1; off < 64; off <<= 1) {
          float u = __shfl_up(incl, off, 64);
          if (lane >= off) incl += u;
        }
        float excl = incl - s3 + carry;
        float4 o;
        o.x = (excl + v.x) * LOG2E; o.y = (excl + s1) * LOG2E;
        o.z = (excl + s2) * LOG2E; o.w = (excl + s3) * LOG2E;
        *(float4*)&out[t0 + lane * 4] = o;
        carry = __shfl(incl, 63, 64) + carry;
      }
    }
    return;
  }

  __shared__ u16 Als[128 * 64];
  __shared__ u16 Bls[128 * 64];
  int m0 = blockIdx.y * 128, n0 = blockIdx.x * 128;
  int tid = threadIdx.x;
  int lane = tid & 63, w = tid >> 6;   // 8 waves
  int wm = w >> 2, wn = w & 3;         // 2 x 4 wave grid: 64 rows x 32 cols each
  int lr = lane & 15, lg = lane >> 4;

  const u16* gA[2]; const u16* gB[2]; u16* lA[2]; u16* lB[2];
#pragma unroll
  for (int j = 0; j < 2; j++) {
    int s = tid + j * 512;
    int row = s >> 3, ch = s & 7;
    int scol = (ch ^ (row & 7)) * 8;
    gA[j] = &A [(size_t)(m0 + row) * DD + scol];
    gB[j] = &Wt[(size_t)(n0 + row) * DD + scol];
    lA[j] = &Als[s * 8];
    lB[j] = &Bls[s * 8];
  }

  f32x4_t acc[4][2];
#pragma unroll
  for (int i = 0; i < 4; i++)
#pragma unroll
    for (int j = 0; j < 2; j++) acc[i][j] = (f32x4_t){0.f, 0.f, 0.f, 0.f};

  for (int kt = 0; kt < DD; kt += 64) {
    __syncthreads();
#pragma unroll
    for (int j = 0; j < 2; j++) {
      async_copy16(gA[j] + kt, lA[j]);
      async_copy16(gB[j] + kt, lB[j]);
    }
    __syncthreads();
#pragma unroll
    for (int kk = 0; kk < 2; kk++) {
      bf16x8_t af[4], bfv[2];
#pragma unroll
      for (int mi = 0; mi < 4; mi++) {
        int row = wm * 64 + mi * 16 + lr;
        int boff = (row * 128 + kk * 64 + lg * 16) ^ ((row & 7) << 4);
        af[mi] = *(const bf16x8_t*)((const char*)Als + boff);
      }
#pragma unroll
      for (int ni = 0; ni < 2; ni++) {
        int row = wn * 32 + ni * 16 + lr;
        int boff = (row * 128 + kk * 64 + lg * 16) ^ ((row & 7) << 4);
        bfv[ni] = *(const bf16x8_t*)((const char*)Bls + boff);
      }
#pragma unroll
      for (int mi = 0; mi < 4; mi++)
#pragma unroll
        for (int ni = 0; ni < 2; ni++)
          acc[mi][ni] = __builtin_amdgcn_mfma_f32_16x16x32_bf16(af[mi], bfv[ni], acc[mi][ni], 0, 0, 0);
    }
  }

  int which = n0 >> 10;
  int nl0 = n0 & 1023;
  if (which == 2) {
    // V: write transposed [bh][hd][n] -- 4 consecutive n per thread = packed 8B store
#pragma unroll
    for (int mi = 0; mi < 4; mi++)
#pragma unroll
      for (int ni = 0; ni < 2; ni++) {
        int gcol = nl0 + wn * 32 + ni * 16 + lr;
        int h = gcol >> 6, hd = gcol & 63;
        int grow0 = m0 + wm * 64 + mi * 16 + lg * 4;
        int b = grow0 >> 11, n = grow0 & (NN - 1);
        ushort4 o4;
        o4.x = f2bf(acc[mi][ni][0]);
        o4.y = f2bf(acc[mi][ni][1]);
        o4.z = f2bf(acc[mi][ni][2]);
        o4.w = f2bf(acc[mi][ni][3]);
        *(ushort4*)&oV[((size_t)(b * HH + h) * HDD + hd) * NN + n] = o4;
      }
  } else {
    u16* outp = which == 0 ? oQ : oK;
#pragma unroll
    for (int mi = 0; mi < 4; mi++)
#pragma unroll
      for (int ni = 0; ni < 2; ni++) {
        int gcol = nl0 + wn * 32 + ni * 16 + lr;
        int h = gcol >> 6, hd = gcol & 63;
#pragma unroll
        for (int r = 0; r < 4; r++) {
          int grow = m0 + wm * 64 + mi * 16 + lg * 4 + r;
          int b = grow >> 11, n = grow & (NN - 1);
          outp[((size_t)(b * HH + h) * NN + n) * HDD + hd] = f2bf(acc[mi][ni][r]);
        }
      }
  }
}

// ---------------- out GEMM 128x64 tile, BK=64, grid 512 = 2 blocks/CU (overlap barrier stalls) ----------------
__global__ __launch_bounds__(512, 4) void gemm_out_kernel(const u16* __restrict__ A,
                                                          const u16* __restrict__ Wt,
                                                          float* __restrict__ oF) {
  __shared__ u16 Als[128 * 64];
  __shared__ u16 Bls[64 * 64];
  int m0 = blockIdx.y * 128, n0 = blockIdx.x * 64;
  int tid = threadIdx.x;
  int lane = tid & 63, w = tid >> 6;   // 8 waves
  int wm = w >> 2, wn = w & 3;         // 2 x 4 wave grid: 64 rows x 16 cols each
  int lr = lane & 15, lg = lane >> 4;

  const u16* gA[2]; u16* lA[2];
#pragma unroll
  for (int j = 0; j < 2; j++) {
    int s = tid + j * 512;
    int row = s >> 3, ch = s & 7;
    int scol = (ch ^ (row & 7)) * 8;
    gA[j] = &A[(size_t)(m0 + row) * DD + scol];
    lA[j] = &Als[s * 8];
  }
  int rowb = tid >> 3, chb = tid & 7;
  const u16* gB = &Wt[(size_t)(n0 + rowb) * DD + ((chb ^ (rowb & 7)) * 8)];
  u16* lB = &Bls[tid * 8];

  f32x4_t acc[4];
#pragma unroll
  for (int i = 0; i < 4; i++) acc[i] = (f32x4_t){0.f, 0.f, 0.f, 0.f};

  for (int kt = 0; kt < DD; kt += 64) {
    __syncthreads();
#pragma unroll
    for (int j = 0; j < 2; j++) async_copy16(gA[j] + kt, lA[j]);
    async_copy16(gB + kt, lB);
    __syncthreads();
#pragma unroll
    for (int kk = 0; kk < 2; kk++) {
      bf16x8_t af[4], bf1;
#pragma unroll
      for (int mi = 0; mi < 4; mi++) {
        int row = wm * 64 + mi * 16 + lr;
        int boff = (row * 128 + kk * 64 + lg * 16) ^ ((row & 7) << 4);
        af[mi] = *(const bf16x8_t*)((const char*)Als + boff);
      }
      {
        int row = wn * 16 + lr;
        int boff = (row * 128 + kk * 64 + lg * 16) ^ ((row & 7) << 4);
        bf1 = *(const bf16x8_t*)((const char*)Bls + boff);
      }
#pragma unroll
      for (int mi = 0; mi < 4; mi++)
        acc[mi] = __builtin_amdgcn_mfma_f32_16x16x32_bf16(af[mi], bf1, acc[mi], 0, 0, 0);
    }
  }

#pragma unroll
  for (int mi = 0; mi < 4; mi++) {
    int gcol = n0 + wn * 16 + lr;
#pragma unroll
    for (int r = 0; r < 4; r++) {
      int grow = m0 + wm * 64 + mi * 16 + lg * 4 + r;
      oF[(size_t)grow * DD + gcol] = acc[mi][r];
    }
  }
}

// ---------------- flash attention: KVBLK=128 (half the barriers), raw v_exp softmax ----------------
// Sequential paired q-tiles (31-p then p); per tile nt = (tile>>1)+1 kv tiles of 128
// (UNIFORM pair total = 17 iters for every p). Even tiles' last kv tile overhangs <=64
// cols past the diagonal -- all reads in-bounds (<=2048), masked via jj>iq AFTER exp
// (garbage-safe). Double-buffered global_load_lds staging (8x16B/thread per tile);
// exp2-domain softmax: cw pre-scaled by log2e, SCL=0.125*log2e, raw v_exp_f32.
__global__ __launch_bounds__(256) void attn_kernel(const u16* __restrict__ Q,
                                                   const u16* __restrict__ K,
                                                   const u16* __restrict__ Vt,
                                                   const float* __restrict__ cw,
                                                   u16* __restrict__ O) {
  __shared__ u16 Kls[2][KVBLK * 64];   // [128 kv rows][64 hd], 16KB each
  __shared__ u16 Vls[2][64 * KVBLK];   // [64 hd][128 kv], 16KB each
  int flat = blockIdx.y * gridDim.x + blockIdx.x;  // grid (16, 32) = 512
  int swz = (flat & 7) * 64 + (flat >> 3);         // bijective, bh-contiguous per XCD
  int pidx = swz & 15, bh = swz >> 4;
  int tid = threadIdx.x;
  int lane = tid & 63, w = tid >> 6;
  int lr = lane & 15, lg = lane >> 4;
  const u16* Qh = Q + (size_t)bh * NN * HDD;
  const u16* Kh = K + (size_t)bh * NN * HDD;
  const u16* Vh = Vt + (size_t)bh * HDD * NN;
  const float* ch = cw + bh * NN;   // pre-scaled by log2e
  int b = bh >> 4, h = bh & 15;

  const float SCL = 0.125f * LOG2E;

  // staging: K tile = 1024 slots of 16B (row=s>>3, chunk=s&7); V tile = 1024 slots
  // (row=s>>4, chunk=s&15). Thread stages slots tid+j*256, j=0..3. LDS linear at
  // slot*16B; swizzle folded into SOURCE chunk: chunk ^ (row&7).
  const u16* gk[4]; const u16* gv[4];
#pragma unroll
  for (int j = 0; j < 4; j++) {
    int s = tid + j * 256;
    int kr = s >> 3, kc = s & 7;
    gk[j] = &Kh[(size_t)kr * HDD + ((kc ^ (kr & 7)) * 8)];
    int vr = s >> 4, vc = s & 15;
    gv[j] = &Vh[(size_t)vr * NN + ((vc ^ (vr & 7)) * 8)];
  }

  for (int which = 0; which < 2; which++) {
    int tile = which == 0 ? (31 - pidx) : pidx;
    int qb = tile * QBLK + w * 16;
    int iq = qb + lr;  // this lane's q-row

    bf16x8_t qf[2];
#pragma unroll
    for (int s = 0; s < 2; s++)
      qf[s] = *(const bf16x8_t*)&Qh[(size_t)iq * HDD + s * 32 + lg * 8];
    float cq = ch[iq];

    float lsum = 0.f;
    f32x4_t oacc[4];
#pragma unroll
    for (int fn = 0; fn < 4; fn++) oacc[fn] = (f32x4_t){0.f, 0.f, 0.f, 0.f};

    int nt = (tile >> 1) + 1;

    // prologue: stage kv tile 0 into buffer 0
#pragma unroll
    for (int j = 0; j < 4; j++) {
      int s = tid + j * 256;
      async_copy16(gk[j], &Kls[0][s * 8]);
      async_copy16(gv[j], &Vls[0][s * 8]);
    }
    __syncthreads();

    int cur = 0;
    for (int kvt = 0; kvt < nt; kvt++) {
      // stage next tile into the other buffer BEFORE computing this one
      if (kvt + 1 < nt) {
        size_t kvn = (size_t)(kvt + 1) * KVBLK;
        int nb = cur ^ 1;
#pragma unroll
        for (int j = 0; j < 4; j++) {
          int s = tid + j * 256;
          async_copy16(gk[j] + kvn * HDD, &Kls[nb][s * 8]);
          async_copy16(gv[j] + kvn, &Vls[nb][s * 8]);
        }
      }
      int kv0 = kvt * KVBLK;
      const u16* Kb = Kls[cur];
      const u16* Vb = Vls[cur];
      float4 ckv[8];
#pragma unroll
      for (int f = 0; f < 8; f++)
        ckv[f] = *(const float4*)&ch[kv0 + f * 16 + lg * 4];

      // S^T = K . Q^T : lane holds col i=lr, rows j = kv0 + f*16 + lg*4 + r  (f=0..7)
      f32x4_t sacc[8];
#pragma unroll
      for (int f = 0; f < 8; f++) sacc[f] = (f32x4_t){0.f, 0.f, 0.f, 0.f};
      __builtin_amdgcn_s_setprio(1);
#pragma unroll
      for (int f = 0; f < 8; f++) {
        int row = f * 16 + lr;
#pragma unroll
        for (int s = 0; s < 2; s++) {
          int boff = (row * 128 + s * 64 + lg * 16) ^ ((row & 7) << 4);
          bf16x8_t kf = *(const bf16x8_t*)((const char*)Kb + boff);
          sacc[f] = __builtin_amdgcn_mfma_f32_16x16x32_bf16(kf, qf[s], sacc[f], 0, 0, 0);
        }
      }
      __builtin_amdgcn_s_setprio(0);

      // fixed-max softmax, exp2 domain: e = 2^(s*SCL + cq - ck); mask AFTER exp
      bool diag = (kvt == nt - 1);
      float pv[8][4];
#pragma unroll
      for (int f = 0; f < 8; f++) {
        const float* ckp = &ckv[f].x;
#pragma unroll
        for (int r = 0; r < 4; r++) {
          float val = fmaf(sacc[f][r], SCL, cq - ckp[r]);
          float e = exp2_raw(val);
          if (diag && (kv0 + f * 16 + lg * 4 + r) > iq) e = 0.f;
          pv[f][r] = e; lsum += e;
        }
      }

      // pack P quarters to bf16 + permlane network -> 4 B-fragments (s covers kv cols 32s..32s+31)
      bf16x8_t pa[4];
#pragma unroll
      for (int s = 0; s < 4; s++) {
        uint32_t x0 = packbf2(pv[2 * s][0], pv[2 * s][1]);
        uint32_t x1 = packbf2(pv[2 * s][2], pv[2 * s][3]);
        uint32_t y0 = packbf2(pv[2 * s + 1][0], pv[2 * s + 1][1]);
        uint32_t y1 = packbf2(pv[2 * s + 1][2], pv[2 * s + 1][3]);
        asm volatile("v_permlane32_swap_b32 %0, %1" : "+v"(x0), "+v"(y0));
        asm volatile("v_permlane32_swap_b32 %0, %1" : "+v"(x1), "+v"(y1));
        asm volatile("v_permlane16_swap_b32 %0, %1" : "+v"(x0), "+v"(y0));
        asm volatile("v_permlane16_swap_b32 %0, %1" : "+v"(x1), "+v"(y1));
        union { uint32_t u[4]; bf16x8_t v; } pk;
        pk.u[0] = x0; pk.u[1] = x1; pk.u[2] = y0; pk.u[3] = y1;
        pa[s] = pk.v;
      }

      // O^T += V^T . P  (V^T rows are 256B; swizzle on within-row offset only)
      __builtin_amdgcn_s_setprio(1);
#pragma unroll
      for (int fn = 0; fn < 4; fn++) {
        int row = fn * 16 + lr;
#pragma unroll
        for (int s = 0; s < 4; s++) {
          int boff = row * 256 + ((s * 64 + lg * 16) ^ ((row & 7) << 4));
          bf16x8_t vf = *(const bf16x8_t*)((const char*)Vb + boff);
          oacc[fn] = __builtin_amdgcn_mfma_f32_16x16x32_bf16(vf, pa[s], oacc[fn], 0, 0, 0);
        }
      }
      __builtin_amdgcn_s_setprio(0);
      __syncthreads();
      cur ^= 1;
    }

    // l-reduce over the 4 lanes sharing lr
    lsum += __shfl_xor(lsum, 16, 64);
    lsum += __shfl_xor(lsum, 32, 64);
    float rinv = 1.0f / lsum;

    // output: lane's q-row iq, hd = fn*16 + lg*4 + r -> packed 8B stores
    u16* orow = O + ((size_t)(b * NN + iq)) * DD + h * HDD;
#pragma unroll
    for (int fn = 0; fn < 4; fn++) {
      ushort4 o4;
      o4.x = f2bf(oacc[fn][0] * rinv);
      o4.y = f2bf(oacc[fn][1] * rinv);
      o4.z = f2bf(oacc[fn][2] * rinv);
      o4.w = f2bf(oacc[fn][3] * rinv);
      *(ushort4*)&orow[fn * 16 + lg * 4] = o4;
    }
  }
}

extern "C" void kernel_launch(void* const* d_in, const int* in_sizes, int n_in,
                              void* d_out, int out_size, void* d_ws, size_t ws_size,
                              hipStream_t stream) {
  const float* x  = (const float*)d_in[0];
  const float* Wq = (const float*)d_in[1];
  const float* Wk = (const float*)d_in[2];
  const float* Wv = (const float*)d_in[3];
  const float* Wo = (const float*)d_in[4];
  const float* Wf = (const float*)d_in[5];
  float* out = (float*)d_out;
  char* ws = (char*)d_ws;
  const size_t MB = 1024 * 1024;
  u16* x_bf  = (u16*)(ws + 0);        // 8 MB
  u16* WqkvT = (u16*)(ws + 8 * MB);   // 6 MB: WqT | WkT | WvT contiguous [3072][1024]; WoT follows
  u16* Qw    = (u16*)(ws + 16 * MB);  // 8 MB [bh][n][hd]
  u16* Kw    = (u16*)(ws + 24 * MB);  // 8 MB
  u16* Vw    = (u16*)(ws + 32 * MB);  // 8 MB [bh][hd][n] (written transposed by gemm)
  u16* Ow    = (u16*)(ws + 40 * MB);  // 8 MB [b n d]
  float* lf  = (float*)(ws + 48 * MB);            // 256 KB
  float* cwp = (float*)(ws + 48 * MB + 262144);   // 256 KB (pre-scaled by log2e)

  // fused prep: logf+cast (4096 blocks) || weight transpose (1024 blocks)
  prep_kernel<<<5120, 256, 0, stream>>>(x, Wf, lf, x_bf, Wq, Wk, Wv, Wo, WqkvT);
  // fused QKV GEMM (cols 0..23) + cumsum (col 24, shadowed): N = 3072; V written transposed
  gemm_kernel<<<dim3(25, 32), 512, 0, stream>>>(x_bf, WqkvT, Qw, Kw, Vw, lf, cwp);
  attn_kernel<<<dim3(16, 32), 256, 0, stream>>>(Qw, Kw, Vw, cwp, Ow);
  gemm_out_kernel<<<dim3(16, 32), 512, 0, stream>>>(Ow, WqkvT + (size_t)3 * DD * DD, out);
}